// Round 1
// baseline (321.146 us; speedup 1.0000x reference)
//
#include <hip/hip_runtime.h>

// Bilinear warp, border_mode='value' (0.0), image NCHW fp32.
// N=32, C=3, H=384, W=512. One thread per (n,y,x); loops over C=3.

#define NN 32
#define CC 3
#define HH 384
#define WW 512

__global__ __launch_bounds__(256) void warp_kernel(
    const float* __restrict__ image,
    const float* __restrict__ flow,
    float* __restrict__ out)
{
    const int HW = HH * WW;
    int idx = blockIdx.x * blockDim.x + threadIdx.x;   // over N*H*W
    if (idx >= NN * HW) return;

    int n = idx / HW;
    int p = idx - n * HW;        // y*W + x
    int y = p / WW;
    int x = p - y * WW;

    const float* fl = flow + (size_t)n * 2 * HW;
    float u = (float)x + fl[p]      * (float)WW;
    float v = (float)y + fl[HW + p] * (float)HH;

    float u0 = floorf(u), v0 = floorf(v);
    float du = u - u0,    dv = v - v0;
    int u0i = (int)u0,    v0i = (int)v0;

    bool valid = (u >= 0.f) && (u <= (float)(WW - 1)) &&
                 (v >= 0.f) && (v <= (float)(HH - 1));

    int x0 = min(max(u0i,     0), WW - 1);
    int x1 = min(max(u0i + 1, 0), WW - 1);
    int y0 = min(max(v0i,     0), HH - 1);
    int y1 = min(max(v0i + 1, 0), HH - 1);

    float w00 = (1.f - du) * (1.f - dv);
    float w10 = du         * (1.f - dv);
    float w01 = (1.f - du) * dv;
    float w11 = du         * dv;

    int i00 = y0 * WW + x0;
    int i10 = y0 * WW + x1;
    int i01 = y1 * WW + x0;
    int i11 = y1 * WW + x1;

    const float* img = image + (size_t)n * CC * HW;
    float*       o   = out   + (size_t)n * CC * HW;

#pragma unroll
    for (int c = 0; c < CC; ++c) {
        const float* ic = img + c * HW;
        float r = w00 * ic[i00] + w10 * ic[i10]
                + w01 * ic[i01] + w11 * ic[i11];
        o[c * HW + p] = valid ? r : 0.f;
    }
}

extern "C" void kernel_launch(void* const* d_in, const int* in_sizes, int n_in,
                              void* d_out, int out_size, void* d_ws, size_t ws_size,
                              hipStream_t stream) {
    const float* image = (const float*)d_in[0];
    const float* flow  = (const float*)d_in[1];
    float* out = (float*)d_out;

    int total = NN * HH * WW;                 // threads = pixels
    int block = 256;
    int grid  = (total + block - 1) / block;
    warp_kernel<<<grid, block, 0, stream>>>(image, flow, out);
}

// Round 3
// 288.577 us; speedup vs baseline: 1.1129x; 1.1129x over previous
//
#include <hip/hip_runtime.h>

// Bilinear warp, border value 0. image (32,3,384,512) fp32 NCHW.
// 4 pixels/thread; float2 row-pair gathers (taps x0,x1 in one load);
// all 24 gathers in flight before consumption.

#define NN 32
#define CC 3
#define HH 384
#define WW 512

typedef float v4f __attribute__((ext_vector_type(4)));
typedef float v2f __attribute__((ext_vector_type(2)));

__global__ __launch_bounds__(256) void warp_kernel(
    const float* __restrict__ image,
    const float* __restrict__ flow,
    float* __restrict__ out)
{
    const int HW = HH * WW;
    int t = blockIdx.x * blockDim.x + threadIdx.x;
    if (t >= (NN * HW) / 4) return;

    int idx = t * 4;
    int n = idx / HW;
    int p = idx - n * HW;        // multiple of 4, = y*W + x
    int y = p / WW;
    int x = p - y * WW;

    const float* fl = flow + (size_t)n * 2 * HW;
    v4f fu4 = *(const v4f*)(fl + p);
    v4f fv4 = *(const v4f*)(fl + HW + p);

    float u[4] = { (float)(x + 0) + fu4.x * (float)WW,
                   (float)(x + 1) + fu4.y * (float)WW,
                   (float)(x + 2) + fu4.z * (float)WW,
                   (float)(x + 3) + fu4.w * (float)WW };
    float v[4] = { (float)y + fv4.x * (float)HH,
                   (float)y + fv4.y * (float)HH,
                   (float)y + fv4.z * (float)HH,
                   (float)y + fv4.w * (float)HH };

    int  rb0[4], rb1[4];
    float w00[4], w10[4], w01[4], w11[4];
    bool hi0[4], hi1[4], valid[4];

#pragma unroll
    for (int i = 0; i < 4; ++i) {
        float u0 = floorf(u[i]), v0 = floorf(v[i]);
        float du = u[i] - u0,    dv = v[i] - v0;
        int u0i = (int)u0, v0i = (int)v0;
        valid[i] = (u[i] >= 0.f) && (u[i] <= (float)(WW - 1)) &&
                   (v[i] >= 0.f) && (v[i] <= (float)(HH - 1));
        int x0 = min(max(u0i,     0), WW - 1);
        int x1 = min(max(u0i + 1, 0), WW - 1);
        int xb = min(x0, WW - 2);          // float2 base never crosses row end
        int y0 = min(max(v0i,     0), HH - 1);
        int y1 = min(max(v0i + 1, 0), HH - 1);
        rb0[i] = y0 * WW + xb;
        rb1[i] = y1 * WW + xb;
        hi0[i] = (x0 > xb);
        hi1[i] = (x1 > xb);
        float eu = 1.f - du, ev = 1.f - dv;
        w00[i] = eu * ev;  w10[i] = du * ev;
        w01[i] = eu * dv;  w11[i] = du * dv;
    }

    const float* img = image + (size_t)n * CC * HW;
    float*       o   = out   + (size_t)n * CC * HW;

    // Issue ALL gathers (3 ch x 4 px x 2 rows = 24 float2) before consuming.
    v2f a[CC][4], b[CC][4];
#pragma unroll
    for (int c = 0; c < CC; ++c) {
        const float* ic = img + c * HW;
#pragma unroll
        for (int i = 0; i < 4; ++i) {
            a[c][i] = *(const v2f*)(ic + rb0[i]);
            b[c][i] = *(const v2f*)(ic + rb1[i]);
        }
    }

#pragma unroll
    for (int c = 0; c < CC; ++c) {
        v4f r;
#pragma unroll
        for (int i = 0; i < 4; ++i) {
            float g00 = hi0[i] ? a[c][i].y : a[c][i].x;
            float g10 = hi1[i] ? a[c][i].y : a[c][i].x;
            float g01 = hi0[i] ? b[c][i].y : b[c][i].x;
            float g11 = hi1[i] ? b[c][i].y : b[c][i].x;
            float res = w00[i] * g00 + w10[i] * g10
                      + w01[i] * g01 + w11[i] * g11;
            r[i] = valid[i] ? res : 0.f;
        }
        __builtin_nontemporal_store(r, (v4f*)(o + c * HW + p));
    }
}

extern "C" void kernel_launch(void* const* d_in, const int* in_sizes, int n_in,
                              void* d_out, int out_size, void* d_ws, size_t ws_size,
                              hipStream_t stream) {
    const float* image = (const float*)d_in[0];
    const float* flow  = (const float*)d_in[1];
    float* out = (float*)d_out;

    int threads = NN * HH * WW / 4;
    int block = 256;
    int grid  = (threads + block - 1) / block;
    warp_kernel<<<grid, block, 0, stream>>>(image, flow, out);
}

// Round 4
// 247.141 us; speedup vs baseline: 1.2994x; 1.1677x over previous
//
#include <hip/hip_runtime.h>

// Bilinear warp, border value 0. image (32,3,384,512) fp32 NCHW.
// 4 px/thread, float2 row-pair gathers, XCD-slab swizzle:
// bid%8 -> XCD slab of 4 images; bid>>3 walks row-pairs in order,
// so each XCD streams one image's gather band through its private L2.

#define NN 32
#define CC 3
#define HH 384
#define WW 512
#define HWSZ (HH * WW)
#define PX_PER_BLOCK 1024
#define BLOCKS_PER_IMG (HWSZ / PX_PER_BLOCK)   // 192
#define IMGS_PER_XCD (NN / 8)                  // 4

typedef float v4f __attribute__((ext_vector_type(4)));
typedef float v2f __attribute__((ext_vector_type(2)));

__global__ __launch_bounds__(256) void warp_kernel(
    const float* __restrict__ image,
    const float* __restrict__ flow,
    float* __restrict__ out)
{
    // --- XCD-slab block swizzle ---
    int bid  = blockIdx.x;
    int xcd  = bid & 7;                 // physical XCD under round-robin dispatch
    int slot = bid >> 3;                // 0 .. 4*192-1 within slab
    int img  = slot / BLOCKS_PER_IMG;   // 0..3 within slab
    int wi   = slot - img * BLOCKS_PER_IMG;
    int n    = xcd * IMGS_PER_XCD + img;

    int p = wi * PX_PER_BLOCK + (int)threadIdx.x * 4;   // y*W + x
    int y = p >> 9;                     // W = 512
    int x = p & (WW - 1);

    const float* fl = flow + (size_t)n * 2 * HWSZ;
    v4f fu4 = __builtin_nontemporal_load((const v4f*)(fl + p));
    v4f fv4 = __builtin_nontemporal_load((const v4f*)(fl + HWSZ + p));

    float u[4] = { (float)(x + 0) + fu4.x * (float)WW,
                   (float)(x + 1) + fu4.y * (float)WW,
                   (float)(x + 2) + fu4.z * (float)WW,
                   (float)(x + 3) + fu4.w * (float)WW };
    float v[4] = { (float)y + fv4.x * (float)HH,
                   (float)y + fv4.y * (float)HH,
                   (float)y + fv4.z * (float)HH,
                   (float)y + fv4.w * (float)HH };

    int  rb0[4], rb1[4];
    float w00[4], w10[4], w01[4], w11[4];
    bool hi0[4], hi1[4], valid[4];

#pragma unroll
    for (int i = 0; i < 4; ++i) {
        float u0 = floorf(u[i]), v0 = floorf(v[i]);
        float du = u[i] - u0,    dv = v[i] - v0;
        int u0i = (int)u0, v0i = (int)v0;
        valid[i] = (u[i] >= 0.f) && (u[i] <= (float)(WW - 1)) &&
                   (v[i] >= 0.f) && (v[i] <= (float)(HH - 1));
        int x0 = min(max(u0i,     0), WW - 1);
        int x1 = min(max(u0i + 1, 0), WW - 1);
        int xb = min(x0, WW - 2);       // float2 base never crosses row end
        int y0 = min(max(v0i,     0), HH - 1);
        int y1 = min(max(v0i + 1, 0), HH - 1);
        rb0[i] = y0 * WW + xb;
        rb1[i] = y1 * WW + xb;
        hi0[i] = (x0 > xb);
        hi1[i] = (x1 > xb);
        float eu = 1.f - du, ev = 1.f - dv;
        w00[i] = eu * ev;  w10[i] = du * ev;
        w01[i] = eu * dv;  w11[i] = du * dv;
    }

    const float* img_b = image + (size_t)n * CC * HWSZ;
    float*       o     = out   + (size_t)n * CC * HWSZ;

    // Issue ALL gathers (3 ch x 4 px x 2 rows = 24 float2) before consuming.
    v2f a[CC][4], b[CC][4];
#pragma unroll
    for (int c = 0; c < CC; ++c) {
        const float* ic = img_b + c * HWSZ;
#pragma unroll
        for (int i = 0; i < 4; ++i) {
            a[c][i] = *(const v2f*)(ic + rb0[i]);
            b[c][i] = *(const v2f*)(ic + rb1[i]);
        }
    }

#pragma unroll
    for (int c = 0; c < CC; ++c) {
        v4f r;
#pragma unroll
        for (int i = 0; i < 4; ++i) {
            float g00 = hi0[i] ? a[c][i].y : a[c][i].x;
            float g10 = hi1[i] ? a[c][i].y : a[c][i].x;
            float g01 = hi0[i] ? b[c][i].y : b[c][i].x;
            float g11 = hi1[i] ? b[c][i].y : b[c][i].x;
            float res = w00[i] * g00 + w10[i] * g10
                      + w01[i] * g01 + w11[i] * g11;
            r[i] = valid[i] ? res : 0.f;
        }
        __builtin_nontemporal_store(r, (v4f*)(o + c * HWSZ + p));
    }
}

extern "C" void kernel_launch(void* const* d_in, const int* in_sizes, int n_in,
                              void* d_out, int out_size, void* d_ws, size_t ws_size,
                              hipStream_t stream) {
    const float* image = (const float*)d_in[0];
    const float* flow  = (const float*)d_in[1];
    float* out = (float*)d_out;

    int grid = NN * HWSZ / PX_PER_BLOCK;    // 6144 blocks, 256 threads each
    warp_kernel<<<grid, 256, 0, stream>>>(image, flow, out);
}

// Round 5
// 215.898 us; speedup vs baseline: 1.4875x; 1.1447x over previous
//
#include <hip/hip_runtime.h>

// Bilinear warp, border value 0. image (32,3,384,512) fp32 NCHW.
// Two-pass: (1) repack image -> bf16 NHWC padded to 4ch (8 B/px) in d_ws;
// (2) warp: per pixel ONE 16B gather per row covers both x-taps x all 3 ch.
// Cuts gather line-transactions ~3x (6 -> 2 taps/px). XCD-slab swizzle kept.

#define NN 32
#define CC 3
#define HH 384
#define WW 512
#define HWSZ (HH * WW)

typedef float v4f __attribute__((ext_vector_type(4)));
typedef float v2f __attribute__((ext_vector_type(2)));
typedef unsigned short v8u __attribute__((ext_vector_type(8), aligned(8)));

__device__ __forceinline__ unsigned short f2bf(float x) {
    unsigned int u = __float_as_uint(x);
    unsigned int r = (u + 0x7FFFu + ((u >> 16) & 1u)) >> 16;   // RNE
    return (unsigned short)r;
}
__device__ __forceinline__ float bf2f(unsigned short b) {
    return __uint_as_float(((unsigned int)b) << 16);
}

// ---- pass 1: NCHW fp32 -> NHWC(pad4) bf16, 4 px/thread, streaming ----
__global__ __launch_bounds__(256) void prep_kernel(
    const float* __restrict__ image, unsigned short* __restrict__ ws)
{
    int t = blockIdx.x * 256 + threadIdx.x;
    int idx4 = t * 4;                      // first pixel (global over N*HW)
    int n = idx4 / HWSZ;
    int p = idx4 - n * HWSZ;
    const float* base = image + (size_t)n * CC * HWSZ;
    v4f c0 = __builtin_nontemporal_load((const v4f*)(base + p));
    v4f c1 = __builtin_nontemporal_load((const v4f*)(base + HWSZ + p));
    v4f c2 = __builtin_nontemporal_load((const v4f*)(base + 2 * HWSZ + p));
    v8u o0 = { f2bf(c0.x), f2bf(c1.x), f2bf(c2.x), 0,
               f2bf(c0.y), f2bf(c1.y), f2bf(c2.y), 0 };
    v8u o1 = { f2bf(c0.z), f2bf(c1.z), f2bf(c2.z), 0,
               f2bf(c0.w), f2bf(c1.w), f2bf(c2.w), 0 };
    unsigned short* w = ws + (size_t)idx4 * 4;
    *(v8u*)(w)     = o0;
    *(v8u*)(w + 8) = o1;
}

// ---- pass 2: warp from bf16 NHWC, 2 px/thread, 2 gathers/px ----
__global__ __launch_bounds__(256) void warp_kernel(
    const unsigned short* __restrict__ ws,
    const float* __restrict__ flow,
    float* __restrict__ out)
{
    // XCD-slab swizzle: bid&7 -> XCD slab of 4 images; 384 blocks/img, 1 row/block.
    int bid  = blockIdx.x;
    int slot = bid >> 3;                   // 0..1535
    int img  = slot / HH;                  // 384 blocks per image (1 row each)
    int wi   = slot - img * HH;            // row index
    int n    = (bid & 7) * 4 + img;

    int y = wi;
    int x = (int)threadIdx.x * 2;
    int p = y * WW + x;

    const float* fl = flow + (size_t)n * 2 * HWSZ;
    v2f fu = __builtin_nontemporal_load((const v2f*)(fl + p));
    v2f fv = __builtin_nontemporal_load((const v2f*)(fl + HWSZ + p));

    const unsigned short* wb = ws + (size_t)n * HWSZ * 4;
    float*                o  = out + (size_t)n * CC * HWSZ;

    v2f r0, r1, r2;
    float* rc[3] = { (float*)&r0, (float*)&r1, (float*)&r2 };

#pragma unroll
    for (int i = 0; i < 2; ++i) {
        float u = (float)(x + i) + ((i == 0) ? fu.x : fu.y) * (float)WW;
        float v = (float)y       + ((i == 0) ? fv.x : fv.y) * (float)HH;
        float u0 = floorf(u), v0 = floorf(v);
        float du = u - u0,    dv = v - v0;
        int u0i = (int)u0, v0i = (int)v0;
        bool valid = (u >= 0.f) && (u <= (float)(WW - 1)) &&
                     (v >= 0.f) && (v <= (float)(HH - 1));
        int x0 = min(max(u0i,     0), WW - 1);
        int x1 = min(max(u0i + 1, 0), WW - 1);
        int xb = min(x0, WW - 2);          // 16B pair never crosses row end
        int y0 = min(max(v0i,     0), HH - 1);
        int y1 = min(max(v0i + 1, 0), HH - 1);
        bool hi0 = (x0 > xb);
        bool hi1 = (x1 > xb);
        float eu = 1.f - du, ev = 1.f - dv;
        float w00 = eu * ev, w10 = du * ev, w01 = eu * dv, w11 = du * dv;

        v8u A = *(const v8u*)(wb + (size_t)(y0 * WW + xb) * 4);
        v8u B = *(const v8u*)(wb + (size_t)(y1 * WW + xb) * 4);

#pragma unroll
        for (int c = 0; c < CC; ++c) {
            float g00 = bf2f(hi0 ? A[4 + c] : A[c]);
            float g10 = bf2f(hi1 ? A[4 + c] : A[c]);
            float g01 = bf2f(hi0 ? B[4 + c] : B[c]);
            float g11 = bf2f(hi1 ? B[4 + c] : B[c]);
            float res = w00 * g00 + w10 * g10 + w01 * g01 + w11 * g11;
            rc[c][i] = valid ? res : 0.f;
        }
    }

    __builtin_nontemporal_store(r0, (v2f*)(o + p));
    __builtin_nontemporal_store(r1, (v2f*)(o + HWSZ + p));
    __builtin_nontemporal_store(r2, (v2f*)(o + 2 * HWSZ + p));
}

// ---- fallback (R3 kernel) if ws is too small ----
__global__ __launch_bounds__(256) void warp_fb(
    const float* __restrict__ image,
    const float* __restrict__ flow,
    float* __restrict__ out)
{
    int bid  = blockIdx.x;
    int slot = bid >> 3;
    int img  = slot / (HWSZ / 1024);
    int wi   = slot - img * (HWSZ / 1024);
    int n    = (bid & 7) * 4 + img;

    int p = wi * 1024 + (int)threadIdx.x * 4;
    int y = p >> 9;
    int x = p & (WW - 1);

    const float* fl = flow + (size_t)n * 2 * HWSZ;
    v4f fu4 = __builtin_nontemporal_load((const v4f*)(fl + p));
    v4f fv4 = __builtin_nontemporal_load((const v4f*)(fl + HWSZ + p));

    float u[4] = { (float)(x + 0) + fu4.x * (float)WW,
                   (float)(x + 1) + fu4.y * (float)WW,
                   (float)(x + 2) + fu4.z * (float)WW,
                   (float)(x + 3) + fu4.w * (float)WW };
    float v[4] = { (float)y + fv4.x * (float)HH,
                   (float)y + fv4.y * (float)HH,
                   (float)y + fv4.z * (float)HH,
                   (float)y + fv4.w * (float)HH };
    int rb0[4], rb1[4];
    float w00[4], w10[4], w01[4], w11[4];
    bool hi0[4], hi1[4], valid[4];
#pragma unroll
    for (int i = 0; i < 4; ++i) {
        float u0 = floorf(u[i]), v0 = floorf(v[i]);
        float du = u[i] - u0, dv = v[i] - v0;
        int u0i = (int)u0, v0i = (int)v0;
        valid[i] = (u[i] >= 0.f) && (u[i] <= (float)(WW - 1)) &&
                   (v[i] >= 0.f) && (v[i] <= (float)(HH - 1));
        int x0 = min(max(u0i, 0), WW - 1);
        int x1 = min(max(u0i + 1, 0), WW - 1);
        int xb = min(x0, WW - 2);
        int y0 = min(max(v0i, 0), HH - 1);
        int y1 = min(max(v0i + 1, 0), HH - 1);
        rb0[i] = y0 * WW + xb; rb1[i] = y1 * WW + xb;
        hi0[i] = (x0 > xb); hi1[i] = (x1 > xb);
        float eu = 1.f - du, ev = 1.f - dv;
        w00[i] = eu * ev; w10[i] = du * ev; w01[i] = eu * dv; w11[i] = du * dv;
    }
    const float* imb = image + (size_t)n * CC * HWSZ;
    float*       o   = out   + (size_t)n * CC * HWSZ;
    v2f a[CC][4], b[CC][4];
#pragma unroll
    for (int c = 0; c < CC; ++c) {
        const float* ic = imb + c * HWSZ;
#pragma unroll
        for (int i = 0; i < 4; ++i) {
            a[c][i] = *(const v2f*)(ic + rb0[i]);
            b[c][i] = *(const v2f*)(ic + rb1[i]);
        }
    }
#pragma unroll
    for (int c = 0; c < CC; ++c) {
        v4f r;
#pragma unroll
        for (int i = 0; i < 4; ++i) {
            float g00 = hi0[i] ? a[c][i].y : a[c][i].x;
            float g10 = hi1[i] ? a[c][i].y : a[c][i].x;
            float g01 = hi0[i] ? b[c][i].y : b[c][i].x;
            float g11 = hi1[i] ? b[c][i].y : b[c][i].x;
            float res = w00[i] * g00 + w10[i] * g10 + w01[i] * g01 + w11[i] * g11;
            r[i] = valid[i] ? res : 0.f;
        }
        __builtin_nontemporal_store(r, (v4f*)(o + c * HWSZ + p));
    }
}

extern "C" void kernel_launch(void* const* d_in, const int* in_sizes, int n_in,
                              void* d_out, int out_size, void* d_ws, size_t ws_size,
                              hipStream_t stream) {
    const float* image = (const float*)d_in[0];
    const float* flow  = (const float*)d_in[1];
    float* out = (float*)d_out;

    const size_t need = (size_t)NN * HWSZ * 4 * sizeof(unsigned short); // 50.3 MB
    if (ws_size >= need) {
        unsigned short* ws = (unsigned short*)d_ws;
        prep_kernel<<<NN * HWSZ / (256 * 4), 256, 0, stream>>>(image, ws);
        warp_kernel<<<NN * HH, 256, 0, stream>>>(ws, flow, out);  // 12288 blocks
    } else {
        warp_fb<<<NN * HWSZ / 1024, 256, 0, stream>>>(image, flow, out);
    }
}